// Round 3
// baseline (1020.339 us; speedup 1.0000x reference)
//
#include <hip/hip_runtime.h>
#include <math.h>

#define NCLS 9

typedef __attribute__((ext_vector_type(8))) short short8;
typedef __attribute__((ext_vector_type(4))) float f32x4;

__device__ __forceinline__ unsigned short f2bf(float f) {
    unsigned int u = __float_as_uint(f);
    return (unsigned short)((u + 0x7fffu + ((u >> 16) & 1u)) >> 16);  // RNE
}

__device__ __forceinline__ short8 as_s8(uint4 v) {
    union { uint4 u; short8 s; } x; x.u = v; return x.s;
}

__device__ __forceinline__ float fast_tanh(float x) {
    float e = __expf(2.0f * x);
    return 1.0f - 2.0f * __builtin_amdgcn_rcpf(e + 1.0f);
}

// Persistent MFMA RNN: 32 blocks x 16 batch rows, 256 threads (4 waves).
// Wave w owns 64 output cols as 4 B-tiles in registers; tile t4's columns are
// col = w*64 + c*4 + t4 (c = lane&15) so each lane's 4 outputs per row are
// consecutive -> one ds_write_b64. A-traffic: 4 waves x 8KB = 32KB/step.
__global__ __launch_bounds__(256, 1) void rnn_mfma_kernel(
    const float* __restrict__ seq,   // [B, T]
    int T,
    const float* __restrict__ W,     // [256]
    const float* __restrict__ U,     // [256,256] row-major
    const float* __restrict__ bias,  // [256]
    float* __restrict__ out)         // [B, 256] fp32
{
    const int tid  = threadIdx.x;
    const int w    = tid >> 6;    // wave 0..3
    const int lane = tid & 63;
    const int g    = lane >> 4;
    const int l16  = lane & 15;
    const int b0   = blockIdx.x << 4;

    __shared__ unsigned char h_lds[2][8192];   // [16 rows][256 k] bf16, XOR-swizzled
    __shared__ float s_chunk[128][16];         // seq prefetch [t][row]

    // ---- one-time: U columns as B-fragments (bf16) in registers ----
    // B-frag (16x16x32): lane l -> tile-col c = l&15, k = kk*32 + (l>>4)*8 + i.
    // Actual column of tile t4, slot c: w*64 + c*4 + t4.
    uint4 bfrag[4][8];
    {
        const int colbase = w * 64 + l16 * 4;
        #pragma unroll
        for (int t4 = 0; t4 < 4; ++t4) {
            #pragma unroll
            for (int kk = 0; kk < 8; ++kk) {
                unsigned int d[4];
                #pragma unroll
                for (int p = 0; p < 4; ++p) {
                    const int k0 = kk * 32 + g * 8 + 2 * p;
                    d[p] = (unsigned)f2bf(U[k0 * 256 + colbase + t4])
                         | ((unsigned)f2bf(U[(k0 + 1) * 256 + colbase + t4]) << 16);
                }
                bfrag[t4][kk] = make_uint4(d[0], d[1], d[2], d[3]);
            }
        }
    }
    #pragma unroll
    for (int t4 = 0; t4 < 4; ++t4)
        #pragma unroll
        for (int kk = 0; kk < 8; ++kk)
            asm volatile("" : "+v"(bfrag[t4][kk].x), "+v"(bfrag[t4][kk].y),
                              "+v"(bfrag[t4][kk].z), "+v"(bfrag[t4][kk].w));

    const float4 wv = *(const float4*)&W[w * 64 + l16 * 4];
    const float4 bv = *(const float4*)&bias[w * 64 + l16 * 4];

    for (int idx = tid; idx < 2048; idx += 256)
        ((unsigned int*)h_lds[0])[idx] = 0u;

    const unsigned swzA  = (unsigned)((l16 & 7) << 4);
    const int      arow  = l16 * 512 + g * 16;
    const int      crow  = g * 4;
    const unsigned wcol2 = (unsigned)((w * 64 + l16 * 4) * 2);

    for (int t = 0; t < T; ++t) {
        if ((t & 127) == 0) {
            for (int idx = tid; idx < 2048; idx += 256) {
                const int dt = idx >> 4, row = idx & 15;
                s_chunk[dt][row] = seq[(b0 + row) * T + (t + dt)];
            }
            __syncthreads();
        }
        const int cur = t & 1;
        const int nxt = cur ^ 1;

        // A-fragments: full h (16x256), 8 x ds_read_b128, swizzled
        uint4 a[8];
        #pragma unroll
        for (int kk = 0; kk < 8; ++kk)
            a[kk] = *(const uint4*)&h_lds[cur][(unsigned)(arow + kk * 64) ^ swzA];

        f32x4 acc[4];
        #pragma unroll
        for (int t4 = 0; t4 < 4; ++t4) acc[t4] = (f32x4){0.f, 0.f, 0.f, 0.f};

        #pragma unroll
        for (int kk = 0; kk < 8; ++kk) {
            #pragma unroll
            for (int t4 = 0; t4 < 4; ++t4)
                acc[t4] = __builtin_amdgcn_mfma_f32_16x16x32_bf16(
                    as_s8(a[kk]), as_s8(bfrag[t4][kk]), acc[t4], 0, 0, 0);
        }

        const float4 sv = *(const float4*)&s_chunk[t & 127][crow];
        const float svr[4] = {sv.x, sv.y, sv.z, sv.w};
        const float wvr[4] = {wv.x, wv.y, wv.z, wv.w};
        const float bvr[4] = {bv.x, bv.y, bv.z, bv.w};

        #pragma unroll
        for (int r = 0; r < 4; ++r) {
            const int row = crow + r;
            float hf[4];
            unsigned short hh[4];
            #pragma unroll
            for (int t4 = 0; t4 < 4; ++t4) {
                const float v = acc[t4][r] + svr[r] * wvr[t4] + bvr[t4];
                hf[t4] = fast_tanh(v);
                hh[t4] = f2bf(hf[t4]);
            }
            const unsigned lo = (unsigned)hh[0] | ((unsigned)hh[1] << 16);
            const unsigned hi = (unsigned)hh[2] | ((unsigned)hh[3] << 16);
            *(uint2*)&h_lds[nxt][(unsigned)(row * 512 + wcol2) ^ (unsigned)((row & 7) << 4)]
                = make_uint2(lo, hi);
            if (t == T - 1) {
                #pragma unroll
                for (int t4 = 0; t4 < 4; ++t4)
                    out[(b0 + row) * 256 + w * 64 + l16 * 4 + t4] = hf[t4];
            }
        }
        __syncthreads();
    }
}

// Tiny MLP head: one block per batch row, 128 threads.
__global__ __launch_bounds__(128) void mlp_kernel(
    const float* __restrict__ h2,
    const float* __restrict__ Wd1, const float* __restrict__ bd1,
    const float* __restrict__ Wd2, const float* __restrict__ bd2,
    const float* __restrict__ Wd3, const float* __restrict__ bd3,
    const float* __restrict__ Wd4, const float* __restrict__ bd4,
    float* __restrict__ out)
{
    const int b   = blockIdx.x;
    const int tid = threadIdx.x;

    __shared__ float hin[256];
    __shared__ float z1[128];
    __shared__ float z2[64];
    __shared__ float z3[32];

    hin[tid]       = h2[b * 256 + tid];
    hin[tid + 128] = h2[b * 256 + tid + 128];
    __syncthreads();

    {
        float a = bd1[tid];
#pragma unroll 8
        for (int i = 0; i < 256; ++i) a += hin[i] * Wd1[i * 128 + tid];
        z1[tid] = fmaxf(a, 0.0f);
    }
    __syncthreads();
    if (tid < 64) {
        float a = bd2[tid];
#pragma unroll 8
        for (int i = 0; i < 128; ++i) a += z1[i] * Wd2[i * 64 + tid];
        z2[tid] = fmaxf(a, 0.0f);
    }
    __syncthreads();
    if (tid < 32) {
        float a = bd3[tid];
#pragma unroll 8
        for (int i = 0; i < 64; ++i) a += z2[i] * Wd3[i * 32 + tid];
        z3[tid] = fmaxf(a, 0.0f);
    }
    __syncthreads();
    if (tid < NCLS) {
        float a = bd4[tid];
#pragma unroll
        for (int i = 0; i < 32; ++i) a += z3[i] * Wd4[i * NCLS + tid];
        out[b * NCLS + tid] = a;
    }
}

extern "C" void kernel_launch(void* const* d_in, const int* in_sizes, int n_in,
                              void* d_out, int out_size, void* d_ws, size_t ws_size,
                              hipStream_t stream) {
    const float* x   = (const float*)d_in[0];
    const float* W1  = (const float*)d_in[1];
    const float* U1  = (const float*)d_in[2];
    const float* b1  = (const float*)d_in[3];
    const float* W2  = (const float*)d_in[4];
    const float* U2  = (const float*)d_in[5];
    const float* b2  = (const float*)d_in[6];
    const float* Wd1 = (const float*)d_in[7];
    const float* bd1 = (const float*)d_in[8];
    const float* Wd2 = (const float*)d_in[9];
    const float* bd2 = (const float*)d_in[10];
    const float* Wd3 = (const float*)d_in[11];
    const float* bd3 = (const float*)d_in[12];
    const float* Wd4 = (const float*)d_in[13];
    const float* bd4 = (const float*)d_in[14];

    float* out = (float*)d_out;
    float* ws  = (float*)d_ws;
    float* h1  = ws;                  // 512*256 fp32
    float* h2  = ws + 512 * 256;      // 512*256 fp32

    rnn_mfma_kernel<<<32, 256, 0, stream>>>(x, 1024, W1, U1, b1, h1);
    rnn_mfma_kernel<<<32, 256, 0, stream>>>(h1, 256, W2, U2, b2, h2);
    mlp_kernel<<<512, 128, 0, stream>>>(h2, Wd1, bd1, Wd2, bd2, Wd3, bd3, Wd4, bd4, out);
}